// Round 3
// baseline (659.475 us; speedup 1.0000x reference)
//
#include <hip/hip_runtime.h>
#include <hip/hip_bf16.h>
#include <stdint.h>

// Problem constants
#define B_  64
#define T_  1000
#define DC_ 512
#define DM_ 80
#define DP_ 128
#define DH_ 128
#define DA_ 128
#define DRN 1024
#define G4  4096

typedef __hip_bfloat16 bf16;

__device__ __forceinline__ float b2f(bf16 v) { return __bfloat162float(v); }
__device__ __forceinline__ bf16  f2b(float v) { return __float2bfloat16(v); }

// dtype-generic load/store (flag: 1 = f32 buffers, 0 = bf16 buffers)
__device__ __forceinline__ float ldv(const float* p, size_t i) { return p[i]; }
__device__ __forceinline__ float ldv(const bf16*  p, size_t i) { return b2f(p[i]); }
__device__ __forceinline__ void  stv(float* p, size_t i, float v) { p[i] = v; }
__device__ __forceinline__ void  stv(bf16*  p, size_t i, float v) { p[i] = f2b(v); }
template<typename T> __device__ __forceinline__ bool skip(const int* flag) {
    return flag[0] != (sizeof(T) == 4 ? 1 : 0);
}

// ---------------- dtype sniff -----------------------------------------------
// h0 = randn*0.1. If buffer is bf16: low 16 bits of each 32b word are a real
// bf16 value -> biased exponent in ~[113,126] for nearly all 256 probes.
// If buffer is f32: low 16 bits are uniform mantissa noise -> exponent field
// uniform over [0,255], only ~10% land in the window.
__global__ void sniff_kernel(const uint32_t* __restrict__ h0raw, int* __restrict__ flag) {
    __shared__ int cnt;
    if (threadIdx.x == 0) cnt = 0;
    __syncthreads();
    int c = 0;
    for (int i = threadIdx.x; i < 256; i += 64) {
        uint32_t u = h0raw[i];
        uint32_t e = (u >> 7) & 0xFF;   // exponent field of low-half-as-bf16
        if (e >= 100 && e <= 126) c++;
    }
    atomicAdd(&cnt, c);
    __syncthreads();
    if (threadIdx.x == 0) flag[0] = (cnt >= 128) ? 0 : 1;  // 0=bf16, 1=f32
}

// ---------------- Threefry-2x32 (JAX semantics, partitionable mode) ----------
__device__ __forceinline__ uint32_t rotl32(uint32_t v, int r) {
    return (v << r) | (v >> (32 - r));
}

__device__ __forceinline__ void threefry2x32(uint32_t k0, uint32_t k1,
                                             uint32_t x0, uint32_t x1,
                                             uint32_t& y0, uint32_t& y1) {
    uint32_t ks2 = k0 ^ k1 ^ 0x1BD11BDAu;
    x0 += k0; x1 += k1;
#define TF_R(r) { x0 += x1; x1 = rotl32(x1, r); x1 ^= x0; }
    TF_R(13) TF_R(15) TF_R(26) TF_R(6)
    x0 += k1; x1 += ks2 + 1u;
    TF_R(17) TF_R(29) TF_R(16) TF_R(24)
    x0 += ks2; x1 += k0 + 2u;
    TF_R(13) TF_R(15) TF_R(26) TF_R(6)
    x0 += k0; x1 += k1 + 3u;
    TF_R(17) TF_R(29) TF_R(16) TF_R(24)
    x0 += k1; x1 += ks2 + 4u;
    TF_R(13) TF_R(15) TF_R(26) TF_R(6)
    x0 += ks2; x1 += k0 + 5u;
#undef TF_R
    y0 = x0; y1 = x1;
}

__device__ __forceinline__ float dropout_mask(int which, int j) {
    uint32_t dk0, dk1, b1, b2;
    threefry2x32(0u, 42u, 0u, (uint32_t)which, dk0, dk1);
    threefry2x32(dk0, dk1, 0u, (uint32_t)j, b1, b2);
    uint32_t bits = b1 ^ b2;
    uint32_t fb = (bits >> 9) | 0x3f800000u;
    float u = __uint_as_float(fb) - 1.0f;
    return (u < 0.5f) ? 2.0f : 0.0f;
}

// ---------------- PreNet: x[64,80] -> x_pre[64,128] (fp32 into ws) ----------
template<typename T>
__global__ void prenet_kernel(const int* __restrict__ flag,
                              const T* __restrict__ x, const T* __restrict__ w1,
                              const T* __restrict__ b1, const T* __restrict__ w2,
                              const T* __restrict__ b2, float* __restrict__ xpre) {
    if (skip<T>(flag)) return;
    __shared__ float xs[DM_];
    __shared__ float hs[DH_];
    int b = blockIdx.x, tid = threadIdx.x;
    if (tid < DM_) xs[tid] = ldv(x, b*DM_ + tid);
    __syncthreads();
    float acc = ldv(b1, tid);
    #pragma unroll 8
    for (int k = 0; k < DM_; ++k) acc = fmaf(xs[k], ldv(w1, k*DH_ + tid), acc);
    acc = fmaxf(acc, 0.f) * dropout_mask(0, b*DH_ + tid);
    hs[tid] = acc;
    __syncthreads();
    float acc2 = ldv(b2, tid);
    #pragma unroll 8
    for (int k = 0; k < DH_; ++k) acc2 = fmaf(hs[k], ldv(w2, k*DP_ + tid), acc2);
    acc2 = fmaxf(acc2, 0.f) * dropout_mask(1, b*DP_ + tid);
    xpre[b*DP_ + tid] = acc2;
}

// ---------------- ctx[b,c] = sum_t w[b,t]*mem[b,t,c] ------------------------
template<typename T>
__global__ void ctx_kernel(const int* __restrict__ flag,
                           const T* __restrict__ mem, const T* __restrict__ w,
                           float* __restrict__ ctxf) {
    if (skip<T>(flag)) return;
    __shared__ float wsh[125];
    int b = blockIdx.y, t0 = blockIdx.x * 125;
    int tid = threadIdx.x;
    if (tid < 125) wsh[tid] = ldv(w, b*T_ + t0 + tid);
    __syncthreads();
    int c = tid;
    float s0 = 0.f, s1 = 0.f;
    for (int t = 0; t < 125; ++t) {
        size_t row = (size_t)(b*T_ + t0 + t)*DC_;
        float wv = wsh[t];
        s0 = fmaf(wv, ldv(mem, row + c), s0);
        s1 = fmaf(wv, ldv(mem, row + c + 256), s1);
    }
    atomicAdd(&ctxf[b*DC_ + c], s0);
    atomicAdd(&ctxf[b*DC_ + c + 256], s1);
}

// ---------------- LSTM gate GEMM: gpart[s][64][4096] partials ----------------
template<typename T>
__global__ void lstm_gemm_kernel(const int* __restrict__ flag,
                                 const float* __restrict__ A1, int L1,
                                 const float* __restrict__ A2, int L2,
                                 const T* __restrict__ Hp,
                                 const T* __restrict__ Wih,
                                 const T* __restrict__ Whh,
                                 float* __restrict__ gpart, int nchunks) {
    if (skip<T>(flag)) return;
    __shared__ float As[64][34];
    __shared__ float Ws[32][64];
    int tid = threadIdx.x;
    int n0b = blockIdx.x * 64;
    int split = blockIdx.y;
    int L12 = L1 + L2;
    int kbase = split * (nchunks * 32);
    int cx = tid & 15, ry = tid >> 4;
    int b0 = ry*4, n0 = cx*4;
    float acc[4][4] = {};
    for (int ch = 0; ch < nchunks; ++ch) {
        int k0 = kbase + ch*32;
        __syncthreads();
        #pragma unroll
        for (int r = 0; r < 8; ++r) {           // stage A (2048 elems)
            int i = r*256 + tid;
            int k = i & 31, bb = i >> 5;
            int kg = k0 + k;
            float v;
            if (kg < L1)       v = A1[bb*L1 + kg];
            else if (kg < L12) v = A2[bb*L2 + (kg - L1)];
            else               v = ldv(Hp, bb*DRN + (kg - L12));
            As[bb][k] = v;
        }
        #pragma unroll
        for (int r = 0; r < 8; ++r) {           // stage W (2048 elems)
            int i = r*256 + tid;
            int n = i & 63, k = i >> 6;
            int kg = k0 + k;
            float v = (kg < L12) ? ldv(Wih, (size_t)kg*G4 + n0b + n)
                                 : ldv(Whh, (size_t)(kg - L12)*G4 + n0b + n);
            Ws[k][n] = v;
        }
        __syncthreads();
        #pragma unroll
        for (int kk = 0; kk < 32; kk += 2) {
            float2 av[4];
            #pragma unroll
            for (int r = 0; r < 4; ++r) av[r] = *(const float2*)&As[b0+r][kk];
            float4 w0 = *(const float4*)&Ws[kk][n0];
            float4 w1 = *(const float4*)&Ws[kk+1][n0];
            #pragma unroll
            for (int r = 0; r < 4; ++r) {
                acc[r][0] = fmaf(av[r].x, w0.x, acc[r][0]); acc[r][0] = fmaf(av[r].y, w1.x, acc[r][0]);
                acc[r][1] = fmaf(av[r].x, w0.y, acc[r][1]); acc[r][1] = fmaf(av[r].y, w1.y, acc[r][1]);
                acc[r][2] = fmaf(av[r].x, w0.z, acc[r][2]); acc[r][2] = fmaf(av[r].y, w1.z, acc[r][2]);
                acc[r][3] = fmaf(av[r].x, w0.w, acc[r][3]); acc[r][3] = fmaf(av[r].y, w1.w, acc[r][3]);
            }
        }
    }
    #pragma unroll
    for (int r = 0; r < 4; ++r) {
        float4 v = make_float4(acc[r][0], acc[r][1], acc[r][2], acc[r][3]);
        *(float4*)&gpart[((size_t)split*B_ + b0 + r)*G4 + n0b + n0] = v;
    }
}

// ---------------- gates + zoneout + outputs ---------------------------------
template<typename T>
__global__ void lstm_gate_kernel(const int* __restrict__ flag,
                                 const float* __restrict__ gpart, const T* __restrict__ bias,
                                 const T* __restrict__ hprev, const T* __restrict__ cprev,
                                 float* __restrict__ hfout, T* __restrict__ hout,
                                 T* __restrict__ cout, T* __restrict__ xdec, int xoff,
                                 const float* __restrict__ ctxf, T* __restrict__ ctxout) {
    if (skip<T>(flag)) return;
    int idx = blockIdx.x*256 + threadIdx.x;     // [0, 65536)
    int b = idx >> 10, u = idx & 1023;
    float gi = ldv(bias, u), gf = ldv(bias, 1024+u), gg = ldv(bias, 2048+u), go = ldv(bias, 3072+u);
    #pragma unroll
    for (int s = 0; s < 4; ++s) {
        const float* g = gpart + ((size_t)s*B_ + b)*G4;
        gi += g[u]; gf += g[1024+u]; gg += g[2048+u]; go += g[3072+u];
    }
    float c = ldv(cprev, idx), h = ldv(hprev, idx);
    float si = 1.f/(1.f + expf(-gi));
    float sf = 1.f/(1.f + expf(-gf));
    float so = 1.f/(1.f + expf(-go));
    float cn = sf*c + si*tanhf(gg);
    float hn = so*tanhf(cn);
    float ho = 0.9f*hn + 0.1f*h;
    float co = 0.9f*cn + 0.1f*c;
    hfout[idx] = ho;
    stv(hout, idx, ho);
    stv(cout, idx, co);
    stv(xdec, b*2560 + xoff + u, ho);
    if (ctxout != nullptr && idx < B_*DC_) stv(ctxout, idx, ctxf[idx]);
}

// ---------------- q = [h0n|h1n] @ att_wq[0:2048,:] ---------------------------
template<typename T>
__global__ void q_kernel(const int* __restrict__ flag,
                         const float* __restrict__ h0f, const float* __restrict__ h1f,
                         const T* __restrict__ wq, float* __restrict__ q) {
    if (skip<T>(flag)) return;
    __shared__ float part[2][DA_];
    int b = blockIdx.x;
    int a = threadIdx.x & 127, half = threadIdx.x >> 7;
    const float* h = half ? h1f : h0f;
    size_t woff = (size_t)half*DRN*DA_;
    float acc = 0.f;
    for (int k = 0; k < DRN; ++k) acc = fmaf(h[b*DRN + k], ldv(wq, woff + (size_t)k*DA_ + a), acc);
    part[half][a] = acc;
    __syncthreads();
    if (half == 0) q[b*DA_ + a] = part[0][a] + part[1][a];
}

// ---------------- fused attention: pm GEMM + tanh-dot + sigmoid --------------
template<typename T>
__global__ void attn_fused_kernel(const int* __restrict__ flag,
                                  const T* __restrict__ mem, const T* __restrict__ wm,
                                  const float* __restrict__ q, const T* __restrict__ ab,
                                  const T* __restrict__ av, float* __restrict__ p) {
    if (skip<T>(flag)) return;
    __shared__ float Ms[32][34];    // mem tile [t][k]
    __shared__ float Bs[32][DA_];   // wm tile [k][a]
    __shared__ float pms[32][132];  // pm tile [t][a]
    __shared__ float qv[DA_], avv[DA_];
    int tid = threadIdx.x;
    int t0 = blockIdx.x * 32, b = blockIdx.y;
    if (tid < DA_) {
        qv[tid]  = q[b*DA_ + tid] + ldv(ab, tid);
        avv[tid] = ldv(av, tid);
    }
    int ty = tid >> 5, tx = tid & 31;
    float acc[4][4] = {};
    for (int kc = 0; kc < DC_; kc += 32) {
        __syncthreads();
        #pragma unroll
        for (int r = 0; r < 4; ++r) {           // stage mem tile (1024 elems)
            int i = r*256 + tid;
            int k = i & 31, t = i >> 5;
            int tg = t0 + t;
            Ms[t][k] = (tg < T_) ? ldv(mem, (size_t)(b*T_ + tg)*DC_ + kc + k) : 0.f;
        }
        #pragma unroll
        for (int r = 0; r < 16; ++r) {          // stage wm tile (4096 elems)
            int i = r*256 + tid;
            int a = i & 127, k = i >> 7;
            Bs[k][a] = ldv(wm, (size_t)(kc + k)*DA_ + a);
        }
        __syncthreads();
        #pragma unroll
        for (int kk = 0; kk < 32; kk += 2) {    // pm: 4x4 register tile
            float2 avx[4];
            #pragma unroll
            for (int r = 0; r < 4; ++r) avx[r] = *(const float2*)&Ms[ty*4+r][kk];
            float4 w0 = *(const float4*)&Bs[kk][tx*4];
            float4 w1 = *(const float4*)&Bs[kk+1][tx*4];
            #pragma unroll
            for (int r = 0; r < 4; ++r) {
                acc[r][0] = fmaf(avx[r].x, w0.x, acc[r][0]); acc[r][0] = fmaf(avx[r].y, w1.x, acc[r][0]);
                acc[r][1] = fmaf(avx[r].x, w0.y, acc[r][1]); acc[r][1] = fmaf(avx[r].y, w1.y, acc[r][1]);
                acc[r][2] = fmaf(avx[r].x, w0.z, acc[r][2]); acc[r][2] = fmaf(avx[r].y, w1.z, acc[r][2]);
                acc[r][3] = fmaf(avx[r].x, w0.w, acc[r][3]); acc[r][3] = fmaf(avx[r].y, w1.w, acc[r][3]);
            }
        }
    }
    #pragma unroll
    for (int r = 0; r < 4; ++r) {
        float4 v = make_float4(acc[r][0], acc[r][1], acc[r][2], acc[r][3]);
        *(float4*)&pms[ty*4+r][tx*4] = v;
    }
    __syncthreads();
    int tl = tid >> 3, aq = tid & 7;
    float s = 0.f;
    #pragma unroll
    for (int j = 0; j < 16; ++j) {
        int a = j*8 + aq;
        s = fmaf(avv[a], tanhf(qv[a] + pms[tl][a]), s);
    }
    s += __shfl_down(s, 4, 8);
    s += __shfl_down(s, 2, 8);
    s += __shfl_down(s, 1, 8);
    if (aq == 0 && (t0 + tl) < T_) {
        p[b*T_ + t0 + tl] = 1.f/(1.f + expf(-s));
    }
}

// ---------------- w_new = w*p + shift(w*(1-p)) -------------------------------
template<typename T>
__global__ void wnew_kernel(const int* __restrict__ flag,
                            const T* __restrict__ w, const float* __restrict__ p,
                            T* __restrict__ wout) {
    if (skip<T>(flag)) return;
    int idx = blockIdx.x*256 + threadIdx.x;
    if (idx >= B_*T_) return;
    int t = idx % T_;
    float val = ldv(w, idx) * p[idx];
    if (t > 0) val = fmaf(ldv(w, idx-1), (1.f - p[idx-1]), val);
    stv(wout, idx, val);
}

// ---------------- launch -----------------------------------------------------
extern "C" void kernel_launch(void* const* d_in, const int* in_sizes, int n_in,
                              void* d_out, int out_size, void* d_ws, size_t ws_size,
                              hipStream_t stream) {
    (void)in_sizes; (void)n_in; (void)out_size; (void)ws_size;

    // workspace (fp32 scratch, dtype-independent): 1,292,801 floats ~= 4.93 MiB
    float* wsf  = (float*)d_ws;
    float* XPRE = wsf;                // 8192
    float* Qb   = wsf + 8192;         // 8192
    float* Pb   = wsf + 16384;        // 64000
    float* Gb   = wsf + 80384;        // 4*64*4096 = 1048576
    float* CTXF = wsf + 1128960;      // 32768
    float* H0F  = wsf + 1161728;      // 65536
    float* H1F  = wsf + 1227264;      // 65536
    int*   FLAG = (int*)(wsf + 1292800);

    // out element offsets: x_dec, ctx, w_new, h0n, c0n, h1n, c1n
    const size_t O_XDEC = 0, O_CTX = 163840, O_WN = 196608, O_H0 = 260608,
                 O_C0 = 326144, O_H1 = 391680, O_C1 = 457216;

    // Zero first 786432 BYTES of out:
    //  f32 out: exactly x_dec + ctx regions (196608 elems * 4B).
    //  bf16 out: elems [0,393216) — x_dec zero-tail kept, rest overwritten later.
    hipMemsetAsync(d_out, 0, 786432, stream);
    hipMemsetAsync(CTXF, 0, 32768*sizeof(float), stream);

    sniff_kernel<<<1, 64, 0, stream>>>((const uint32_t*)d_in[2], FLAG);

#define LAUNCH_BOTH(expr_f, expr_b) do { expr_f; expr_b; } while (0)

    // f32-typed views
    const float *f_x = (const float*)d_in[0], *f_w = (const float*)d_in[1],
                *f_h0 = (const float*)d_in[2], *f_c0 = (const float*)d_in[3],
                *f_h1 = (const float*)d_in[4], *f_c1 = (const float*)d_in[5],
                *f_mem = (const float*)d_in[6],
                *f_pw1 = (const float*)d_in[8], *f_pb1 = (const float*)d_in[9],
                *f_pw2 = (const float*)d_in[10], *f_pb2 = (const float*)d_in[11],
                *f_wih0 = (const float*)d_in[12], *f_whh0 = (const float*)d_in[13],
                *f_b0 = (const float*)d_in[14],
                *f_wih1 = (const float*)d_in[15], *f_whh1 = (const float*)d_in[16],
                *f_b1 = (const float*)d_in[17],
                *f_wq = (const float*)d_in[18], *f_wm = (const float*)d_in[19],
                *f_ab = (const float*)d_in[20], *f_av = (const float*)d_in[21];
    float* f_out = (float*)d_out;

    // bf16-typed views
    const bf16 *b_x = (const bf16*)d_in[0], *b_w = (const bf16*)d_in[1],
               *b_h0 = (const bf16*)d_in[2], *b_c0 = (const bf16*)d_in[3],
               *b_h1 = (const bf16*)d_in[4], *b_c1 = (const bf16*)d_in[5],
               *b_mem = (const bf16*)d_in[6],
               *b_pw1 = (const bf16*)d_in[8], *b_pb1 = (const bf16*)d_in[9],
               *b_pw2 = (const bf16*)d_in[10], *b_pb2 = (const bf16*)d_in[11],
               *b_wih0 = (const bf16*)d_in[12], *b_whh0 = (const bf16*)d_in[13],
               *b_b0 = (const bf16*)d_in[14],
               *b_wih1 = (const bf16*)d_in[15], *b_whh1 = (const bf16*)d_in[16],
               *b_b1 = (const bf16*)d_in[17],
               *b_wq = (const bf16*)d_in[18], *b_wm = (const bf16*)d_in[19],
               *b_ab = (const bf16*)d_in[20], *b_av = (const bf16*)d_in[21];
    bf16* b_out = (bf16*)d_out;

    LAUNCH_BOTH(
        (prenet_kernel<float><<<64, 128, 0, stream>>>(FLAG, f_x, f_pw1, f_pb1, f_pw2, f_pb2, XPRE)),
        (prenet_kernel<bf16 ><<<64, 128, 0, stream>>>(FLAG, b_x, b_pw1, b_pb1, b_pw2, b_pb2, XPRE)));
    LAUNCH_BOTH(
        (ctx_kernel<float><<<dim3(8, 64), 256, 0, stream>>>(FLAG, f_mem, f_w, CTXF)),
        (ctx_kernel<bf16 ><<<dim3(8, 64), 256, 0, stream>>>(FLAG, b_mem, b_w, CTXF)));
    LAUNCH_BOTH(
        (lstm_gemm_kernel<float><<<dim3(64, 4), 256, 0, stream>>>(FLAG, XPRE, 128, CTXF, 512, f_h0, f_wih0, f_whh0, Gb, 13)),
        (lstm_gemm_kernel<bf16 ><<<dim3(64, 4), 256, 0, stream>>>(FLAG, XPRE, 128, CTXF, 512, b_h0, b_wih0, b_whh0, Gb, 13)));
    LAUNCH_BOTH(
        (lstm_gate_kernel<float><<<256, 256, 0, stream>>>(FLAG, Gb, f_b0, f_h0, f_c0, H0F, f_out+O_H0, f_out+O_C0, f_out+O_XDEC, 0, CTXF, f_out+O_CTX)),
        (lstm_gate_kernel<bf16 ><<<256, 256, 0, stream>>>(FLAG, Gb, b_b0, b_h0, b_c0, H0F, b_out+O_H0, b_out+O_C0, b_out+O_XDEC, 0, CTXF, b_out+O_CTX)));
    LAUNCH_BOTH(
        (lstm_gemm_kernel<float><<<dim3(64, 4), 256, 0, stream>>>(FLAG, H0F, 1024, CTXF, 512, f_h1, f_wih1, f_whh1, Gb, 20)),
        (lstm_gemm_kernel<bf16 ><<<dim3(64, 4), 256, 0, stream>>>(FLAG, H0F, 1024, CTXF, 512, b_h1, b_wih1, b_whh1, Gb, 20)));
    LAUNCH_BOTH(
        (lstm_gate_kernel<float><<<256, 256, 0, stream>>>(FLAG, Gb, f_b1, f_h1, f_c1, H1F, f_out+O_H1, f_out+O_C1, f_out+O_XDEC, 1024, nullptr, (float*)nullptr)),
        (lstm_gate_kernel<bf16 ><<<256, 256, 0, stream>>>(FLAG, Gb, b_b1, b_h1, b_c1, H1F, b_out+O_H1, b_out+O_C1, b_out+O_XDEC, 1024, nullptr, (bf16*)nullptr)));
    LAUNCH_BOTH(
        (q_kernel<float><<<64, 256, 0, stream>>>(FLAG, H0F, H1F, f_wq, Qb)),
        (q_kernel<bf16 ><<<64, 256, 0, stream>>>(FLAG, H0F, H1F, b_wq, Qb)));
    LAUNCH_BOTH(
        (attn_fused_kernel<float><<<dim3(32, 64), 256, 0, stream>>>(FLAG, f_mem, f_wm, Qb, f_ab, f_av, Pb)),
        (attn_fused_kernel<bf16 ><<<dim3(32, 64), 256, 0, stream>>>(FLAG, b_mem, b_wm, Qb, b_ab, b_av, Pb)));
    LAUNCH_BOTH(
        (wnew_kernel<float><<<250, 256, 0, stream>>>(FLAG, f_w, Pb, f_out+O_WN)),
        (wnew_kernel<bf16 ><<<250, 256, 0, stream>>>(FLAG, b_w, Pb, b_out+O_WN)));
#undef LAUNCH_BOTH
}

// Round 4
// 449.392 us; speedup vs baseline: 1.4675x; 1.4675x over previous
//
#include <hip/hip_runtime.h>
#include <hip/hip_bf16.h>
#include <stdint.h>

// Problem constants
#define B_  64
#define T_  1000
#define DC_ 512
#define DM_ 80
#define DP_ 128
#define DH_ 128
#define DA_ 128
#define DRN 1024
#define G4  4096

typedef __hip_bfloat16 bf16;
typedef unsigned short u16;
typedef unsigned int   u32;

// MFMA fragment types (per guide: short8 = 8 bf16 = 4 VGPRs)
typedef short bf8_t __attribute__((ext_vector_type(8)));
typedef float f4_t  __attribute__((ext_vector_type(4)));

__device__ __forceinline__ float b2f(bf16 v) { return __bfloat162float(v); }
__device__ __forceinline__ bf16  f2b(float v) { return __float2bfloat16(v); }
__device__ __forceinline__ u16   f2bu(float v) { return __builtin_bit_cast(u16, __float2bfloat16(v)); }
__device__ __forceinline__ float bu2f(u16 u) { return __uint_as_float((u32)u << 16); }

// dtype-generic scalar load/store
__device__ __forceinline__ float ldv(const float* p, size_t i) { return p[i]; }
__device__ __forceinline__ float ldv(const bf16*  p, size_t i) { return b2f(p[i]); }
__device__ __forceinline__ void  stv(float* p, size_t i, float v) { p[i] = v; }
__device__ __forceinline__ void  stv(bf16*  p, size_t i, float v) { p[i] = f2b(v); }
template<typename T> __device__ __forceinline__ bool skip(const int* flag) {
    return flag[0] != (sizeof(T) == 4 ? 1 : 0);
}

// load 8 consecutive elems (i must be 8-aligned) as packed bf16 bits
template<typename T>
__device__ __forceinline__ uint4 ld8bf(const T* p, size_t i) {
    if constexpr (sizeof(T) == 2) {
        return *(const uint4*)((const u16*)p + i);
    } else {
        float4 a = *(const float4*)(p + i);
        float4 b = *(const float4*)(p + i + 4);
        uint4 r;
        r.x = (u32)f2bu(a.x) | ((u32)f2bu(a.y) << 16);
        r.y = (u32)f2bu(a.z) | ((u32)f2bu(a.w) << 16);
        r.z = (u32)f2bu(b.x) | ((u32)f2bu(b.y) << 16);
        r.w = (u32)f2bu(b.z) | ((u32)f2bu(b.w) << 16);
        return r;
    }
}
// load 8 consecutive elems as f32
template<typename T>
__device__ __forceinline__ void ld8f(const T* p, size_t i, float* o) {
    if constexpr (sizeof(T) == 2) {
        uint4 u = *(const uint4*)((const u16*)p + i);
        o[0] = __uint_as_float(u.x << 16); o[1] = __uint_as_float(u.x & 0xffff0000u);
        o[2] = __uint_as_float(u.y << 16); o[3] = __uint_as_float(u.y & 0xffff0000u);
        o[4] = __uint_as_float(u.z << 16); o[5] = __uint_as_float(u.z & 0xffff0000u);
        o[6] = __uint_as_float(u.w << 16); o[7] = __uint_as_float(u.w & 0xffff0000u);
    } else {
        float4 a = *(const float4*)(p + i);
        float4 b = *(const float4*)(p + i + 4);
        o[0]=a.x; o[1]=a.y; o[2]=a.z; o[3]=a.w; o[4]=b.x; o[5]=b.y; o[6]=b.z; o[7]=b.w;
    }
}
__device__ __forceinline__ void ld8f_bits(const u16* p, size_t i, float* o) {
    uint4 u = *(const uint4*)(p + i);
    o[0] = __uint_as_float(u.x << 16); o[1] = __uint_as_float(u.x & 0xffff0000u);
    o[2] = __uint_as_float(u.y << 16); o[3] = __uint_as_float(u.y & 0xffff0000u);
    o[4] = __uint_as_float(u.z << 16); o[5] = __uint_as_float(u.z & 0xffff0000u);
    o[6] = __uint_as_float(u.w << 16); o[7] = __uint_as_float(u.w & 0xffff0000u);
}

// ---------------- dtype sniff (proven round 3; FLAG=0 means bf16) -----------
__global__ void sniff_kernel(const u32* __restrict__ h0raw, int* __restrict__ flag) {
    __shared__ int cnt;
    if (threadIdx.x == 0) cnt = 0;
    __syncthreads();
    int c = 0;
    for (int i = threadIdx.x; i < 256; i += 64) {
        u32 e = (h0raw[i] >> 7) & 0xFF;
        if (e >= 100 && e <= 126) c++;
    }
    atomicAdd(&cnt, c);
    __syncthreads();
    if (threadIdx.x == 0) flag[0] = (cnt >= 128) ? 0 : 1;
}

// ---------------- Threefry-2x32 (bit-exact vs JAX — do not touch) ------------
__device__ __forceinline__ u32 rotl32(u32 v, int r) { return (v << r) | (v >> (32 - r)); }
__device__ __forceinline__ void threefry2x32(u32 k0, u32 k1, u32 x0, u32 x1, u32& y0, u32& y1) {
    u32 ks2 = k0 ^ k1 ^ 0x1BD11BDAu;
    x0 += k0; x1 += k1;
#define TF_R(r) { x0 += x1; x1 = rotl32(x1, r); x1 ^= x0; }
    TF_R(13) TF_R(15) TF_R(26) TF_R(6)
    x0 += k1; x1 += ks2 + 1u;
    TF_R(17) TF_R(29) TF_R(16) TF_R(24)
    x0 += ks2; x1 += k0 + 2u;
    TF_R(13) TF_R(15) TF_R(26) TF_R(6)
    x0 += k0; x1 += k1 + 3u;
    TF_R(17) TF_R(29) TF_R(16) TF_R(24)
    x0 += k1; x1 += ks2 + 4u;
    TF_R(13) TF_R(15) TF_R(26) TF_R(6)
    x0 += ks2; x1 += k0 + 5u;
#undef TF_R
    y0 = x0; y1 = x1;
}
__device__ __forceinline__ float dropout_mask(int which, int j) {
    u32 dk0, dk1, b1, b2;
    threefry2x32(0u, 42u, 0u, (u32)which, dk0, dk1);
    threefry2x32(dk0, dk1, 0u, (u32)j, b1, b2);
    u32 bits = b1 ^ b2;
    float u = __uint_as_float((bits >> 9) | 0x3f800000u) - 1.0f;
    return (u < 0.5f) ? 2.0f : 0.0f;
}

// ---------------- BT prep: wm,wq -> MFMA B-fragment order --------------------
// BTwm[((at*16+kc)*64+L)*8+j] = wm[kc*32+(L>>4)*8+j][at*16+(L&15)]   (at<8,kc<16)
// BTwq[((at*64+kc)*64+L)*8+j] = wq[kc*32+(L>>4)*8+j][at*16+(L&15)]   (at<8,kc<64)
template<typename T>
__global__ void btprep_kernel(const int* __restrict__ flag,
                              const T* __restrict__ wm, const T* __restrict__ wq,
                              u16* __restrict__ BTwm, u16* __restrict__ BTwq) {
    if (skip<T>(flag)) return;
    int gid = blockIdx.x * 256 + threadIdx.x;
    const T* src; u16* dst; int L, kc, at;
    if (gid < 8192) { L = gid & 63; kc = (gid >> 6) & 15; at = gid >> 10; src = wm; dst = BTwm + (size_t)gid * 8; }
    else { int g = gid - 8192; L = g & 63; kc = (g >> 6) & 63; at = g >> 12; src = wq; dst = BTwq + (size_t)g * 8; }
    int col = at * 16 + (L & 15);
    int krow = kc * 32 + (L >> 4) * 8;
    u16 v[8];
    #pragma unroll
    for (int j = 0; j < 8; ++j) v[j] = f2bu(ldv(src, (size_t)(krow + j) * DA_ + col));
    uint4 pk;
    pk.x = v[0] | ((u32)v[1] << 16); pk.y = v[2] | ((u32)v[3] << 16);
    pk.z = v[4] | ((u32)v[5] << 16); pk.w = v[6] | ((u32)v[7] << 16);
    *(uint4*)dst = pk;
}

// ---------------- PreNet: x[64,80] -> Abuf0 cols 0..127 ----------------------
template<typename T>
__global__ void prenet_kernel(const int* __restrict__ flag,
                              const T* __restrict__ x, const T* __restrict__ w1,
                              const T* __restrict__ b1, const T* __restrict__ w2,
                              const T* __restrict__ b2, u16* __restrict__ Ab0) {
    if (skip<T>(flag)) return;
    __shared__ float xs[DM_];
    __shared__ float hs[DH_];
    int b = blockIdx.x, tid = threadIdx.x;
    if (tid < DM_) xs[tid] = ldv(x, b*DM_ + tid);
    __syncthreads();
    float acc = ldv(b1, tid);
    #pragma unroll 8
    for (int k = 0; k < DM_; ++k) acc = fmaf(xs[k], ldv(w1, k*DH_ + tid), acc);
    acc = fmaxf(acc, 0.f) * dropout_mask(0, b*DH_ + tid);
    hs[tid] = acc;
    __syncthreads();
    float acc2 = ldv(b2, tid);
    #pragma unroll 8
    for (int k = 0; k < DH_; ++k) acc2 = fmaf(hs[k], ldv(w2, k*DP_ + tid), acc2);
    acc2 = fmaxf(acc2, 0.f) * dropout_mask(1, b*DP_ + tid);
    Ab0[(size_t)b*1664 + tid] = f2bu(acc2);
}

// ---------------- ctx[b,c] = sum_t w[b,t]*mem[b,t,c], vectorized -------------
// grid (16 t-tiles of 64, 64 b), 256 thr: cg=tid&63 (8 c), tg=tid>>6 (16 t)
template<typename T>
__global__ void ctx_kernel(const int* __restrict__ flag,
                           const T* __restrict__ mem, const T* __restrict__ w,
                           float* __restrict__ ctxf) {
    if (skip<T>(flag)) return;
    __shared__ float wsh[64];
    __shared__ float part[4][512];
    int b = blockIdx.y, t0 = blockIdx.x * 64;
    int tid = threadIdx.x;
    if (tid < 64) wsh[tid] = (t0 + tid < T_) ? ldv(w, b*T_ + t0 + tid) : 0.f;
    __syncthreads();
    int cg = tid & 63, tg = tid >> 6;
    float acc[8] = {};
    for (int i = 0; i < 16; ++i) {
        int t = t0 + tg*16 + i;
        if (t < T_) {
            float v[8];
            ld8f(mem, (size_t)(b*T_ + t)*DC_ + cg*8, v);
            float wv = wsh[tg*16 + i];
            #pragma unroll
            for (int j = 0; j < 8; ++j) acc[j] = fmaf(wv, v[j], acc[j]);
        }
    }
    #pragma unroll
    for (int j = 0; j < 8; ++j) part[tg][cg*8 + j] = acc[j];
    __syncthreads();
    int c = tid * 2;
    float s0 = part[0][c] + part[1][c] + part[2][c] + part[3][c];
    float s1 = part[0][c+1] + part[1][c+1] + part[2][c+1] + part[3][c+1];
    atomicAdd(&ctxf[b*DC_ + c], s0);
    atomicAdd(&ctxf[b*DC_ + c + 1], s1);
}

// ---------------- pack0: ctx + hprev copies into A-buffers, ctx out ----------
template<typename T>
__global__ void pack0_kernel(const int* __restrict__ flag,
                             const float* __restrict__ ctxf,
                             const T* __restrict__ h0p, const T* __restrict__ h1p,
                             u16* __restrict__ Ab0, u16* __restrict__ Ab1,
                             T* __restrict__ ctxout) {
    if (skip<T>(flag)) return;
    int b = blockIdx.x, tid = threadIdx.x;
    for (int c = tid; c < DC_; c += 256) {
        float v = ctxf[b*DC_ + c];
        u16 bv = f2bu(v);
        Ab0[(size_t)b*1664 + 128 + c] = bv;
        Ab1[(size_t)b*2560 + 1024 + c] = bv;
        stv(ctxout, b*DC_ + c, v);
    }
    for (int u = tid; u < DRN; u += 256) {
        Ab0[(size_t)b*1664 + 640 + u]  = f2bu(ldv(h0p, b*DRN + u));
        Ab1[(size_t)b*2560 + 1536 + u] = f2bu(ldv(h1p, b*DRN + u));
    }
}

// ---------------- LSTM gate GEMM (fp32, packed-A, split-K atomics) -----------
// C[64][4096] += A[64][K]@[Wih;Whh]; grid (64 n-tiles of 64, 4 ksplit), 256 thr
template<typename T>
__global__ void lstm_gemm_kernel(const int* __restrict__ flag,
                                 const u16* __restrict__ Abuf, int K, int L12,
                                 const T* __restrict__ Wih, const T* __restrict__ Whh,
                                 float* __restrict__ Gb, int nchunks) {
    if (skip<T>(flag)) return;
    __shared__ float As[64][34];
    __shared__ float Ws[32][64];
    int tid = threadIdx.x;
    int n0b = blockIdx.x * 64;
    int kbase = blockIdx.y * (nchunks * 32);
    int cx = tid & 15, ry = tid >> 4;
    int b0 = ry*4, n0 = cx*4;
    int a_bb = tid >> 2, a_k8 = (tid & 3) * 8;      // A stage: 64 rows x 32 k
    int w_k  = tid >> 3, w_n8 = (tid & 7) * 8;      // W stage: 32 k x 64 n
    float acc[4][4] = {};
    for (int ch = 0; ch < nchunks; ++ch) {
        int k0 = kbase + ch*32;
        __syncthreads();
        {
            float v[8];
            ld8f_bits(Abuf, (size_t)a_bb*K + k0 + a_k8, v);
            #pragma unroll
            for (int j = 0; j < 8; ++j) As[a_bb][a_k8 + j] = v[j];
            int kg = k0 + w_k;
            const T* wr = (kg < L12) ? (Wih + (size_t)kg*G4) : (Whh + (size_t)(kg - L12)*G4);
            ld8f(wr, n0b + w_n8, v);
            #pragma unroll
            for (int j = 0; j < 8; ++j) Ws[w_k][w_n8 + j] = v[j];
        }
        __syncthreads();
        #pragma unroll
        for (int kk = 0; kk < 32; kk += 2) {
            float2 av[4];
            #pragma unroll
            for (int r = 0; r < 4; ++r) av[r] = *(const float2*)&As[b0+r][kk];
            float4 w0 = *(const float4*)&Ws[kk][n0];
            float4 w1 = *(const float4*)&Ws[kk+1][n0];
            #pragma unroll
            for (int r = 0; r < 4; ++r) {
                acc[r][0] = fmaf(av[r].x, w0.x, acc[r][0]); acc[r][0] = fmaf(av[r].y, w1.x, acc[r][0]);
                acc[r][1] = fmaf(av[r].x, w0.y, acc[r][1]); acc[r][1] = fmaf(av[r].y, w1.y, acc[r][1]);
                acc[r][2] = fmaf(av[r].x, w0.z, acc[r][2]); acc[r][2] = fmaf(av[r].y, w1.z, acc[r][2]);
                acc[r][3] = fmaf(av[r].x, w0.w, acc[r][3]); acc[r][3] = fmaf(av[r].y, w1.w, acc[r][3]);
            }
        }
    }
    #pragma unroll
    for (int r = 0; r < 4; ++r)
        #pragma unroll
        for (int j = 0; j < 4; ++j)
            atomicAdd(&Gb[(size_t)(b0 + r)*G4 + n0b + n0 + j], acc[r][j]);
}

// ---------------- gates + zoneout + outputs ---------------------------------
template<typename T>
__global__ void lstm_gate_kernel(const int* __restrict__ flag,
                                 const float* __restrict__ Gb, const T* __restrict__ bias,
                                 const T* __restrict__ hprev, const T* __restrict__ cprev,
                                 T* __restrict__ hout, T* __restrict__ cout,
                                 T* __restrict__ xdec, int xoff,
                                 u16* __restrict__ Hcat, int hoff,
                                 u16* __restrict__ Ab1) {
    if (skip<T>(flag)) return;
    int idx = blockIdx.x*256 + threadIdx.x;     // [0, 65536)
    int b = idx >> 10, u = idx & 1023;
    const float* g = Gb + (size_t)b*G4;
    float gi = ldv(bias, u)        + g[u];
    float gf = ldv(bias, 1024 + u) + g[1024 + u];
    float gg = ldv(bias, 2048 + u) + g[2048 + u];
    float go = ldv(bias, 3072 + u) + g[3072 + u];
    float c = ldv(cprev, idx), h = ldv(hprev, idx);
    float si = 1.f/(1.f + expf(-gi));
    float sf = 1.f/(1.f + expf(-gf));
    float so = 1.f/(1.f + expf(-go));
    float cn = sf*c + si*tanhf(gg);
    float hn = so*tanhf(cn);
    float ho = 0.9f*hn + 0.1f*h;
    float co = 0.9f*cn + 0.1f*c;
    stv(hout, idx, ho);
    stv(cout, idx, co);
    stv(xdec, b*2560 + xoff + u, ho);
    u16 hb = f2bu(ho);
    Hcat[(size_t)b*2048 + hoff + u] = hb;
    if (Ab1 != nullptr) Ab1[(size_t)b*2560 + u] = hb;
}

// ---------------- q GEMM (MFMA): Qb[64][128] = Hcat[64][2048] @ wq -----------
// grid 8 (ksplit of 256), 256 thr = 4 waves; wave w -> m-tile w, 8 a-tiles
template<typename T>
__global__ void qgemm_kernel(const int* __restrict__ flag,
                             const u16* __restrict__ Hcat, const u16* __restrict__ BTwq,
                             float* __restrict__ Qb) {
    if (skip<T>(flag)) return;
    int tid = threadIdx.x;
    int w = tid >> 6, L = tid & 63;
    int m = L & 15, q16 = L >> 4;
    f4_t acc[8];
    #pragma unroll
    for (int at = 0; at < 8; ++at) acc[at] = (f4_t){0.f, 0.f, 0.f, 0.f};
    for (int kcl = 0; kcl < 8; ++kcl) {
        int kc = blockIdx.x * 8 + kcl;
        bf8_t af = *(const bf8_t*)(Hcat + (size_t)(w*16 + m)*2048 + kc*32 + q16*8);
        #pragma unroll
        for (int at = 0; at < 8; ++at) {
            bf8_t bfrag = *(const bf8_t*)(BTwq + ((size_t)(at*64 + kc)*64 + L)*8);
            acc[at] = __builtin_amdgcn_mfma_f32_16x16x32_bf16(af, bfrag, acc[at], 0, 0, 0);
        }
    }
    #pragma unroll
    for (int at = 0; at < 8; ++at)
        #pragma unroll
        for (int r = 0; r < 4; ++r)
            atomicAdd(&Qb[(w*16 + q16*4 + r)*DA_ + at*16 + m], acc[at][r]);
}

// ---------------- fused attention (MFMA pm + tanh-dot + sigmoid) -------------
// grid (16 t-tiles of 64, 64 b), 256 thr = 4 waves. Two half-K staging phases.
template<typename T>
__global__ void attn_kernel(const int* __restrict__ flag,
                            const T* __restrict__ mem, const u16* __restrict__ BTwm,
                            const float* __restrict__ Qb, const T* __restrict__ ab,
                            const T* __restrict__ av, float* __restrict__ p) {
    if (skip<T>(flag)) return;
    __shared__ u16 Alds[64 * 264];       // 64 t-rows x 256 c + 8 pad
    __shared__ float qa[DA_], avl[DA_];
    int tid = threadIdx.x;
    int b = blockIdx.y, t0 = blockIdx.x * 64;
    if (tid < DA_) {
        qa[tid]  = Qb[b*DA_ + tid] + ldv(ab, tid);
        avl[tid] = ldv(av, tid);
    }
    int w = tid >> 6, L = tid & 63;
    int m = L & 15, q16 = L >> 4;
    f4_t acc[8];
    #pragma unroll
    for (int at = 0; at < 8; ++at) acc[at] = (f4_t){0.f, 0.f, 0.f, 0.f};
    for (int ph = 0; ph < 2; ++ph) {
        __syncthreads();
        // stage 64 rows x 256 c (bf16): 2048 uint4, 8 per thread
        #pragma unroll
        for (int rr = 0; rr < 8; ++rr) {
            int i = rr*256 + tid;
            int row = i >> 5, c16 = i & 31;
            int t = t0 + row;
            uint4 v = (t < T_) ? ld8bf(mem, (size_t)(b*T_ + t)*DC_ + ph*256 + c16*8)
                               : make_uint4(0u, 0u, 0u, 0u);
            *(uint4*)(Alds + row*264 + c16*8) = v;
        }
        __syncthreads();
        for (int kcl = 0; kcl < 8; ++kcl) {
            int kc = ph*8 + kcl;
            bf8_t af = *(const bf8_t*)(Alds + (w*16 + m)*264 + kcl*32 + q16*8);
            #pragma unroll
            for (int at = 0; at < 8; ++at) {
                bf8_t bfrag = *(const bf8_t*)(BTwm + ((size_t)(at*16 + kc)*64 + L)*8);
                acc[at] = __builtin_amdgcn_mfma_f32_16x16x32_bf16(af, bfrag, acc[at], 0, 0, 0);
            }
        }
    }
    // epilogue: e[t] = sum_a avl[a]*tanh(qa[a] + pm[t][a]); p = sigmoid(e)
    #pragma unroll
    for (int r = 0; r < 4; ++r) {
        float s = 0.f;
        #pragma unroll
        for (int at = 0; at < 8; ++at) {
            int a = at*16 + m;
            s = fmaf(avl[a], tanhf(qa[a] + acc[at][r]), s);
        }
        s += __shfl_xor(s, 1);
        s += __shfl_xor(s, 2);
        s += __shfl_xor(s, 4);
        s += __shfl_xor(s, 8);
        int t = t0 + w*16 + q16*4 + r;
        if (m == 0 && t < T_) p[b*T_ + t] = 1.f/(1.f + expf(-s));
    }
}

// ---------------- w_new = w*p + shift(w*(1-p)) -------------------------------
template<typename T>
__global__ void wnew_kernel(const int* __restrict__ flag,
                            const T* __restrict__ w, const float* __restrict__ p,
                            T* __restrict__ wout) {
    if (skip<T>(flag)) return;
    int idx = blockIdx.x*256 + threadIdx.x;
    if (idx >= B_*T_) return;
    int t = idx % T_;
    float val = ldv(w, idx) * p[idx];
    if (t > 0) val = fmaf(ldv(w, idx-1), (1.f - p[idx-1]), val);
    stv(wout, idx, val);
}

// ---------------- launch -----------------------------------------------------
extern "C" void kernel_launch(void* const* d_in, const int* in_sizes, int n_in,
                              void* d_out, int out_size, void* d_ws, size_t ws_size,
                              hipStream_t stream) {
    (void)in_sizes; (void)n_in; (void)out_size; (void)ws_size;

    // workspace layout (f32 units). Total 993,793 f32 = 3.79 MiB.
    float* wsf  = (float*)d_ws;
    float* GB0  = wsf;                    // 262144 (zeroed)
    float* GB1  = wsf + 262144;           // 262144 (zeroed)
    float* CTXF = wsf + 524288;           // 32768  (zeroed)
    float* Qb   = wsf + 557056;           // 8192   (zeroed)
    float* Pb   = wsf + 565248;           // 64000
    u16*   AB0  = (u16*)(wsf + 629248);   // 64x1664 bf16
    u16*   AB1  = (u16*)(wsf + 682496);   // 64x2560 bf16
    u16*   HCAT = (u16*)(wsf + 764416);   // 64x2048 bf16
    u16*   BTWM = (u16*)(wsf + 829952);   // 65536 bf16
    u16*   BTWQ = (u16*)(wsf + 862720);   // 262144 bf16
    int*   FLAG = (int*)(wsf + 993792);

    // out element offsets: x_dec, ctx, w_new, h0n, c0n, h1n, c1n
    const size_t O_XDEC = 0, O_CTX = 163840, O_WN = 196608, O_H0 = 260608,
                 O_C0 = 326144, O_H1 = 391680, O_C1 = 457216;

    hipMemsetAsync(d_out, 0, 786432, stream);               // x_dec zero-tail + ctx
    hipMemsetAsync(wsf, 0, 565248 * sizeof(float), stream); // GB0,GB1,CTXF,Qb

    sniff_kernel<<<1, 64, 0, stream>>>((const u32*)d_in[2], FLAG);

    // f32 views
    const float *f_x = (const float*)d_in[0], *f_w = (const float*)d_in[1],
                *f_h0 = (const float*)d_in[2], *f_c0 = (const float*)d_in[3],
                *f_h1 = (const float*)d_in[4], *f_c1 = (const float*)d_in[5],
                *f_mem = (const float*)d_in[6],
                *f_pw1 = (const float*)d_in[8], *f_pb1 = (const float*)d_in[9],
                *f_pw2 = (const float*)d_in[10], *f_pb2 = (const float*)d_in[11],
                *f_wih0 = (const float*)d_in[12], *f_whh0 = (const float*)d_in[13],
                *f_b0 = (const float*)d_in[14],
                *f_wih1 = (const float*)d_in[15], *f_whh1 = (const float*)d_in[16],
                *f_b1 = (const float*)d_in[17],
                *f_wq = (const float*)d_in[18], *f_wm = (const float*)d_in[19],
                *f_ab = (const float*)d_in[20], *f_av = (const float*)d_in[21];
    float* f_out = (float*)d_out;

    // bf16 views
    const bf16 *b_x = (const bf16*)d_in[0], *b_w = (const bf16*)d_in[1],
               *b_h0 = (const bf16*)d_in[2], *b_c0 = (const bf16*)d_in[3],
               *b_h1 = (const bf16*)d_in[4], *b_c1 = (const bf16*)d_in[5],
               *b_mem = (const bf16*)d_in[6],
               *b_pw1 = (const bf16*)d_in[8], *b_pb1 = (const bf16*)d_in[9],
               *b_pw2 = (const bf16*)d_in[10], *b_pb2 = (const bf16*)d_in[11],
               *b_wih0 = (const bf16*)d_in[12], *b_whh0 = (const bf16*)d_in[13],
               *b_b0 = (const bf16*)d_in[14],
               *b_wih1 = (const bf16*)d_in[15], *b_whh1 = (const bf16*)d_in[16],
               *b_b1 = (const bf16*)d_in[17],
               *b_wq = (const bf16*)d_in[18], *b_wm = (const bf16*)d_in[19],
               *b_ab = (const bf16*)d_in[20], *b_av = (const bf16*)d_in[21];
    bf16* b_out = (bf16*)d_out;

#define BOTH(ef, eb) do { ef; eb; } while (0)
    BOTH((btprep_kernel<float><<<160, 256, 0, stream>>>(FLAG, f_wm, f_wq, BTWM, BTWQ)),
         (btprep_kernel<bf16 ><<<160, 256, 0, stream>>>(FLAG, b_wm, b_wq, BTWM, BTWQ)));
    BOTH((prenet_kernel<float><<<64, 128, 0, stream>>>(FLAG, f_x, f_pw1, f_pb1, f_pw2, f_pb2, AB0)),
         (prenet_kernel<bf16 ><<<64, 128, 0, stream>>>(FLAG, b_x, b_pw1, b_pb1, b_pw2, b_pb2, AB0)));
    BOTH((ctx_kernel<float><<<dim3(16, 64), 256, 0, stream>>>(FLAG, f_mem, f_w, CTXF)),
         (ctx_kernel<bf16 ><<<dim3(16, 64), 256, 0, stream>>>(FLAG, b_mem, b_w, CTXF)));
    BOTH((pack0_kernel<float><<<64, 256, 0, stream>>>(FLAG, CTXF, f_h0, f_h1, AB0, AB1, f_out + O_CTX)),
         (pack0_kernel<bf16 ><<<64, 256, 0, stream>>>(FLAG, CTXF, b_h0, b_h1, AB0, AB1, b_out + O_CTX)));
    BOTH((lstm_gemm_kernel<float><<<dim3(64, 4), 256, 0, stream>>>(FLAG, AB0, 1664, 640, f_wih0, f_whh0, GB0, 13)),
         (lstm_gemm_kernel<bf16 ><<<dim3(64, 4), 256, 0, stream>>>(FLAG, AB0, 1664, 640, b_wih0, b_whh0, GB0, 13)));
    BOTH((lstm_gate_kernel<float><<<256, 256, 0, stream>>>(FLAG, GB0, f_b0, f_h0, f_c0, f_out+O_H0, f_out+O_C0, f_out+O_XDEC, 0, HCAT, 0, AB1)),
         (lstm_gate_kernel<bf16 ><<<256, 256, 0, stream>>>(FLAG, GB0, b_b0, b_h0, b_c0, b_out+O_H0, b_out+O_C0, b_out+O_XDEC, 0, HCAT, 0, AB1)));
    BOTH((lstm_gemm_kernel<float><<<dim3(64, 4), 256, 0, stream>>>(FLAG, AB1, 2560, 1536, f_wih1, f_whh1, GB1, 20)),
         (lstm_gemm_kernel<bf16 ><<<dim3(64, 4), 256, 0, stream>>>(FLAG, AB1, 2560, 1536, b_wih1, b_whh1, GB1, 20)));
    BOTH((lstm_gate_kernel<float><<<256, 256, 0, stream>>>(FLAG, GB1, f_b1, f_h1, f_c1, f_out+O_H1, f_out+O_C1, f_out+O_XDEC, 1024, HCAT, 1024, (u16*)nullptr)),
         (lstm_gate_kernel<bf16 ><<<256, 256, 0, stream>>>(FLAG, GB1, b_b1, b_h1, b_c1, b_out+O_H1, b_out+O_C1, b_out+O_XDEC, 1024, HCAT, 1024, (u16*)nullptr)));
    BOTH((qgemm_kernel<float><<<8, 256, 0, stream>>>(FLAG, HCAT, BTWQ, Qb)),
         (qgemm_kernel<bf16 ><<<8, 256, 0, stream>>>(FLAG, HCAT, BTWQ, Qb)));
    BOTH((attn_kernel<float><<<dim3(16, 64), 256, 0, stream>>>(FLAG, f_mem, BTWM, Qb, f_ab, f_av, Pb)),
         (attn_kernel<bf16 ><<<dim3(16, 64), 256, 0, stream>>>(FLAG, b_mem, BTWM, Qb, b_ab, b_av, Pb)));
    BOTH((wnew_kernel<float><<<250, 256, 0, stream>>>(FLAG, f_w, Pb, f_out + O_WN)),
         (wnew_kernel<bf16 ><<<250, 256, 0, stream>>>(FLAG, b_w, Pb, b_out + O_WN)));
#undef BOTH
}